// Round 1
// baseline (245.366 us; speedup 1.0000x reference)
//
#include <hip/hip_runtime.h>
#include <hip/hip_bf16.h>

// Problem: y = (softmax((xW_q)(xW_k)^T / 8) + B) @ (xW_v), b=2 s=2048 d=1024 h=16 hd=64
// Strategy: bf16 MFMA throughout (threshold 9.56e-2 permits).
//   k0a: x f32 -> bf16
//   k0b: W [1024][3072] f32 -> Wt [3072][1024] bf16 (transpose for contiguous-K frags)
//   k1 : QKV GEMM 128x128 tile, XOR-swizzled LDS, writes Q/K/V bf16 [b*h][s][hd] + bias
//   k2 : fused attention, two accumulators: O_s (online softmax) + O_b (bias@V, no rescale)
// Workspace: xb 8MB + Wt 6MB + Q/K/V 24MB = ~38MB.

typedef __attribute__((ext_vector_type(4))) float  f32x4;
typedef __attribute__((ext_vector_type(8))) short  bf16x8;
typedef __attribute__((ext_vector_type(4))) short  s16x4;

__device__ inline short f2bf(float f) {
    __hip_bfloat16 h = __float2bfloat16(f);
    return __builtin_bit_cast(short, h);
}

// ---------------- k0a: convert x to bf16 ----------------
__global__ void conv_x_kernel(const float* __restrict__ x, short* __restrict__ xb) {
    int idx = blockIdx.x * 256 + threadIdx.x;     // 1,048,576 threads, 4 f32 each
    f32x4 v = *reinterpret_cast<const f32x4*>(x + (size_t)idx * 4);
    s16x4 o;
    o[0] = f2bf(v[0]); o[1] = f2bf(v[1]); o[2] = f2bf(v[2]); o[3] = f2bf(v[3]);
    *reinterpret_cast<s16x4*>(xb + (size_t)idx * 4) = o;
}

// ---------------- k0b: transpose W -> Wt bf16 ----------------
__global__ void wtrans_kernel(const float* __restrict__ W, short* __restrict__ Wt) {
    __shared__ float tile[64][65];
    int kb = blockIdx.x;          // 16 k-tiles of 64
    int nb = blockIdx.y;          // 48 n-tiles of 64
    int t = threadIdx.x;
    int c4 = (t & 15) * 4;
    int r0 = t >> 4;              // 0..15
#pragma unroll
    for (int rr = 0; rr < 4; ++rr) {
        int kl = r0 + rr * 16;
        f32x4 v = *reinterpret_cast<const f32x4*>(W + (size_t)(kb * 64 + kl) * 3072 + nb * 64 + c4);
        tile[kl][c4 + 0] = v[0]; tile[kl][c4 + 1] = v[1];
        tile[kl][c4 + 2] = v[2]; tile[kl][c4 + 3] = v[3];
    }
    __syncthreads();
#pragma unroll
    for (int rr = 0; rr < 4; ++rr) {
        int nl = r0 + rr * 16;
        s16x4 o;
#pragma unroll
        for (int i = 0; i < 4; ++i) o[i] = f2bf(tile[c4 + i][nl]);
        *reinterpret_cast<s16x4*>(Wt + (size_t)(nb * 64 + nl) * 1024 + kb * 64 + c4) = o;
    }
}

// ---------------- k1: QKV GEMM ----------------
// M=4096 (b*s), N=3072, K=1024. BM=BN=128, BK=64. 4 waves = 2x2 of 64x64.
__global__ __launch_bounds__(256) void qkv_gemm_kernel(
    const short* __restrict__ xb, const short* __restrict__ Wt,
    const float* __restrict__ bias,
    short* __restrict__ Qo, short* __restrict__ Ko, short* __restrict__ Vo)
{
    __shared__ short As[128 * 64];
    __shared__ short Bs[128 * 64];
    int tid = threadIdx.x;
    int wave = tid >> 6, lane = tid & 63, g = lane >> 4, lr = lane & 15;
    int wr = wave >> 1, wc = wave & 1;
    int bm = blockIdx.x, bn = blockIdx.y;

    f32x4 acc[4][4];
#pragma unroll
    for (int a = 0; a < 4; ++a)
#pragma unroll
        for (int b = 0; b < 4; ++b) acc[a][b] = (f32x4){0.f, 0.f, 0.f, 0.f};

    for (int k0 = 0; k0 < 1024; k0 += 64) {
#pragma unroll
        for (int j = 0; j < 4; ++j) {
            int c = tid + 256 * j;            // 0..1023 chunks of 8 bf16
            int row = c >> 3, cc = c & 7;
            bf16x8 va = *reinterpret_cast<const bf16x8*>(xb + (size_t)(bm * 128 + row) * 1024 + k0 + cc * 8);
            *reinterpret_cast<bf16x8*>(&As[row * 64 + ((cc ^ (row & 7)) * 8)]) = va;
            bf16x8 vb = *reinterpret_cast<const bf16x8*>(Wt + (size_t)(bn * 128 + row) * 1024 + k0 + cc * 8);
            *reinterpret_cast<bf16x8*>(&Bs[row * 64 + ((cc ^ (row & 7)) * 8)]) = vb;
        }
        __syncthreads();

        bf16x8 af[2][4], bfr[2][4];
#pragma unroll
        for (int mt = 0; mt < 4; ++mt) {
            int row = wr * 64 + mt * 16 + lr;
            af[0][mt] = *reinterpret_cast<const bf16x8*>(&As[row * 64 + (((g    ) ^ (lr & 7)) * 8)]);
            af[1][mt] = *reinterpret_cast<const bf16x8*>(&As[row * 64 + (((g + 4) ^ (lr & 7)) * 8)]);
        }
#pragma unroll
        for (int nt = 0; nt < 4; ++nt) {
            int row = wc * 64 + nt * 16 + lr;
            bfr[0][nt] = *reinterpret_cast<const bf16x8*>(&Bs[row * 64 + (((g    ) ^ (lr & 7)) * 8)]);
            bfr[1][nt] = *reinterpret_cast<const bf16x8*>(&Bs[row * 64 + (((g + 4) ^ (lr & 7)) * 8)]);
        }
#pragma unroll
        for (int mt = 0; mt < 4; ++mt)
#pragma unroll
            for (int nt = 0; nt < 4; ++nt) {
                acc[mt][nt] = __builtin_amdgcn_mfma_f32_16x16x32_bf16(af[0][mt], bfr[0][nt], acc[mt][nt], 0, 0, 0);
                acc[mt][nt] = __builtin_amdgcn_mfma_f32_16x16x32_bf16(af[1][mt], bfr[1][nt], acc[mt][nt], 0, 0, 0);
            }
        __syncthreads();
    }

    // epilogue: add bias, scatter to Q/K/V bf16 [b*16+h][s][64]
#pragma unroll
    for (int nt = 0; nt < 4; ++nt) {
        int n = bn * 128 + wc * 64 + nt * 16 + lr;
        float bv = bias[n];
        int which = n >> 10;
        int h = (n >> 6) & 15;
        int dd = n & 63;
        short* base = (which == 0) ? Qo : (which == 1) ? Ko : Vo;
#pragma unroll
        for (int mt = 0; mt < 4; ++mt) {
#pragma unroll
            for (int r = 0; r < 4; ++r) {
                int m = bm * 128 + wr * 64 + mt * 16 + g * 4 + r;
                int bb = m >> 11, s = m & 2047;
                float v = acc[mt][nt][r] + bv;
                base[(((size_t)bb * 16 + h) * 2048 + s) * 64 + dd] = f2bf(v);
            }
        }
    }
}

// ---------------- k2: fused attention ----------------
// grid (32 qtiles, 32 bh). 4 waves, each owns 16 q rows. KV tiles of 64.
__global__ __launch_bounds__(256) void attn_kernel(
    const short* __restrict__ Qw, const short* __restrict__ Kw, const short* __restrict__ Vw,
    const float* __restrict__ attnB, float* __restrict__ out)
{
    __shared__ short Ks [64][64];     // [key][d], d-chunks XOR-swizzled
    __shared__ short Vts[64][64];     // [d][key], key-chunks XOR-swizzled
    __shared__ short Ps [4][16][64];  // per-wave P, key-chunks XOR-swizzled

    int qt = blockIdx.x;              // 0..31
    int bh = blockIdx.y;              // 0..31
    int b = bh >> 4, h = bh & 15;
    int tid = threadIdx.x;
    int wave = tid >> 6, lane = tid & 63, g = lane >> 4, lr = lane & 15;

    const short* Qbase = Qw + (size_t)bh * 2048 * 64;
    const short* Kbase = Kw + (size_t)bh * 2048 * 64;
    const short* Vbase = Vw + (size_t)bh * 2048 * 64;
    const float* Bbase = attnB + (size_t)bh * 2048 * 2048;

    int qbase = qt * 64 + wave * 16;  // this wave's 16 q rows

    // Q fragments: A-frag row = lr, k = g*8+i (+32)
    bf16x8 qf[2];
    {
        const short* qp = Qbase + (size_t)(qbase + lr) * 64 + g * 8;
        qf[0] = *reinterpret_cast<const bf16x8*>(qp);
        qf[1] = *reinterpret_cast<const bf16x8*>(qp + 32);
    }

    f32x4 Os[4], Ob[4];
#pragma unroll
    for (int dt = 0; dt < 4; ++dt) { Os[dt] = (f32x4){0.f,0.f,0.f,0.f}; Ob[dt] = (f32x4){0.f,0.f,0.f,0.f}; }
    float mrun[4], lrun[4];
#pragma unroll
    for (int r = 0; r < 4; ++r) { mrun[r] = -1e30f; lrun[r] = 0.f; }

    for (int kt = 0; kt < 32; ++kt) {
        // ---- stage K tile (row-major, swizzled d-chunks) ----
#pragma unroll
        for (int j = 0; j < 2; ++j) {
            int c = tid + 256 * j;            // 0..511
            int row = c >> 3, cc = c & 7;
            bf16x8 v = *reinterpret_cast<const bf16x8*>(Kbase + (size_t)(kt * 64 + row) * 64 + cc * 8);
            *reinterpret_cast<bf16x8*>(&Ks[row][(cc ^ (row & 7)) * 8]) = v;
        }
        // ---- stage V transposed (Vts[d][key], swizzled key-chunks) ----
#pragma unroll
        for (int j = 0; j < 2; ++j) {
            int c = tid + 256 * j;
            int key = c & 63, cc = c >> 6;    // cc = d-chunk 0..7
            bf16x8 v = *reinterpret_cast<const bf16x8*>(Vbase + (size_t)(kt * 64 + key) * 64 + cc * 8);
#pragma unroll
            for (int i = 0; i < 8; ++i) {
                int d = cc * 8 + i;
                Vts[d][(((key >> 3) ^ (d & 7)) * 8) + (key & 7)] = v[i];
            }
        }
        __syncthreads();

        // ---- issue bias loads early (independent of LDS) ----
        f32x4 bfl[4];
        {
            const float* bp = Bbase + (size_t)(qbase + lr) * 2048 + kt * 64 + g * 8;
            bfl[0] = *reinterpret_cast<const f32x4*>(bp);
            bfl[1] = *reinterpret_cast<const f32x4*>(bp + 4);
            bfl[2] = *reinterpret_cast<const f32x4*>(bp + 32);
            bfl[3] = *reinterpret_cast<const f32x4*>(bp + 36);
        }

        // ---- QK^T: S[16q][64keys] per wave ----
        f32x4 S[4];
#pragma unroll
        for (int nt = 0; nt < 4; ++nt) {
            int krow = nt * 16 + lr;
            bf16x8 kf0 = *reinterpret_cast<const bf16x8*>(&Ks[krow][(((g    ) ^ (lr & 7)) * 8)]);
            bf16x8 kf1 = *reinterpret_cast<const bf16x8*>(&Ks[krow][(((g + 4) ^ (lr & 7)) * 8)]);
            f32x4 s = (f32x4){0.f,0.f,0.f,0.f};
            s = __builtin_amdgcn_mfma_f32_16x16x32_bf16(qf[0], kf0, s, 0, 0, 0);
            s = __builtin_amdgcn_mfma_f32_16x16x32_bf16(qf[1], kf1, s, 0, 0, 0);
            S[nt] = s;
        }

        // ---- online softmax (rows live across 16-lane groups) ----
#pragma unroll
        for (int nt = 0; nt < 4; ++nt)
#pragma unroll
            for (int r = 0; r < 4; ++r) S[nt][r] *= 0.125f;

#pragma unroll
        for (int r = 0; r < 4; ++r) {
            float mx = fmaxf(fmaxf(S[0][r], S[1][r]), fmaxf(S[2][r], S[3][r]));
            mx = fmaxf(mx, __shfl_xor(mx, 1));
            mx = fmaxf(mx, __shfl_xor(mx, 2));
            mx = fmaxf(mx, __shfl_xor(mx, 4));
            mx = fmaxf(mx, __shfl_xor(mx, 8));
            float newm = fmaxf(mrun[r], mx);
            float sf = __expf(mrun[r] - newm);
            mrun[r] = newm;
            float rs = 0.f;
#pragma unroll
            for (int nt = 0; nt < 4; ++nt) {
                float p = __expf(S[nt][r] - newm);
                S[nt][r] = p;
                rs += p;
            }
            rs += __shfl_xor(rs, 1);
            rs += __shfl_xor(rs, 2);
            rs += __shfl_xor(rs, 4);
            rs += __shfl_xor(rs, 8);
            lrun[r] = lrun[r] * sf + rs;
#pragma unroll
            for (int dt = 0; dt < 4; ++dt) Os[dt][r] *= sf;
        }

        // ---- P -> LDS (bf16), per-wave private region ----
#pragma unroll
        for (int nt = 0; nt < 4; ++nt) {
#pragma unroll
            for (int r = 0; r < 4; ++r) {
                int q = g * 4 + r;
                int col = nt * 16 + lr;
                Ps[wave][q][(((col >> 3) ^ (q & 7)) * 8) + (col & 7)] = f2bf(S[nt][r]);
            }
        }

        // ---- bias -> bf16 A-fragments ----
        bf16x8 bbf[2];
#pragma unroll
        for (int i = 0; i < 4; ++i) {
            bbf[0][i]     = f2bf(bfl[0][i]);
            bbf[0][i + 4] = f2bf(bfl[1][i]);
            bbf[1][i]     = f2bf(bfl[2][i]);
            bbf[1][i + 4] = f2bf(bfl[3][i]);
        }

        // ---- PV + BV ----
        bf16x8 pf0 = *reinterpret_cast<const bf16x8*>(&Ps[wave][lr][(((g    ) ^ (lr & 7)) * 8)]);
        bf16x8 pf1 = *reinterpret_cast<const bf16x8*>(&Ps[wave][lr][(((g + 4) ^ (lr & 7)) * 8)]);
#pragma unroll
        for (int dt = 0; dt < 4; ++dt) {
            int vrow = dt * 16 + lr;
            bf16x8 v0 = *reinterpret_cast<const bf16x8*>(&Vts[vrow][(((g    ) ^ (lr & 7)) * 8)]);
            bf16x8 v1 = *reinterpret_cast<const bf16x8*>(&Vts[vrow][(((g + 4) ^ (lr & 7)) * 8)]);
            Os[dt] = __builtin_amdgcn_mfma_f32_16x16x32_bf16(pf0,    v0, Os[dt], 0, 0, 0);
            Os[dt] = __builtin_amdgcn_mfma_f32_16x16x32_bf16(pf1,    v1, Os[dt], 0, 0, 0);
            Ob[dt] = __builtin_amdgcn_mfma_f32_16x16x32_bf16(bbf[0], v0, Ob[dt], 0, 0, 0);
            Ob[dt] = __builtin_amdgcn_mfma_f32_16x16x32_bf16(bbf[1], v1, Ob[dt], 0, 0, 0);
        }
        __syncthreads();
    }

    // ---- epilogue: y = Os/l + Ob, out [b][s][h*64+dd] f32 ----
#pragma unroll
    for (int dt = 0; dt < 4; ++dt) {
#pragma unroll
        for (int r = 0; r < 4; ++r) {
            int q = qbase + g * 4 + r;
            int dcol = dt * 16 + lr;
            float v = Os[dt][r] / lrun[r] + Ob[dt][r];
            out[((size_t)(b * 2048 + q) * 16 + h) * 64 + dcol] = v;
        }
    }
}

extern "C" void kernel_launch(void* const* d_in, const int* in_sizes, int n_in,
                              void* d_out, int out_size, void* d_ws, size_t ws_size,
                              hipStream_t stream) {
    const float* x     = (const float*)d_in[0];
    const float* attnB = (const float*)d_in[1];
    const float* W     = (const float*)d_in[2];
    const float* bias  = (const float*)d_in[3];
    float* out = (float*)d_out;

    short* ws = (short*)d_ws;
    short* xb = ws;                               // 4,194,304 shorts
    short* Wt = xb + 4194304;                     // 3,145,728 shorts
    short* Q  = Wt + 3145728;                     // 4,194,304 each
    short* K  = Q  + 4194304;
    short* V  = K  + 4194304;
    // total ~38MB of d_ws

    conv_x_kernel<<<4096, 256, 0, stream>>>(x, xb);
    wtrans_kernel<<<dim3(16, 48), 256, 0, stream>>>(W, Wt);
    qkv_gemm_kernel<<<dim3(32, 24), 256, 0, stream>>>(xb, Wt, bias, Q, K, V);
    attn_kernel<<<dim3(32, 32), 256, 0, stream>>>(Q, K, V, attnB, out);
}

// Round 2
// 228.567 us; speedup vs baseline: 1.0735x; 1.0735x over previous
//
#include <hip/hip_runtime.h>
#include <hip/hip_bf16.h>

// y = (softmax((xWq)(xWk)^T/8) + B) @ (xWv); b=2 s=2048 d=1024 h=16 hd=64
// Pipeline:
//   conv_x : x f32 -> bf16
//   wtrans : W [1024][3072] f32 -> Wt [3072][1024] bf16
//   qkv_gemm: 128x128 tile, BK=64, global_load_lds(16B) w/ pre-swizzled source (m97)
//   vtrans : V [bh][s][64] -> Vt [bh][64][s]
//   attn   : dbuf LDS, 1 barrier/iter, no-max softmax (exact in f32), split
//            accumulators Os (softmax@V) + Ob (B@V), bias streamed once.

typedef __attribute__((ext_vector_type(4))) float  f32x4;
typedef __attribute__((ext_vector_type(8))) short  bf16x8;
typedef __attribute__((ext_vector_type(4))) short  s16x4;

__device__ __forceinline__ short f2bf(float f) {
    __hip_bfloat16 h = __float2bfloat16(f);
    return __builtin_bit_cast(short, h);
}

__device__ __forceinline__ void gll16(const short* g, short* l) {
    __builtin_amdgcn_global_load_lds(
        (const __attribute__((address_space(1))) void*)g,
        (__attribute__((address_space(3))) void*)l, 16, 0, 0);
}

// ---------------- conv_x ----------------
__global__ void conv_x_kernel(const float* __restrict__ x, short* __restrict__ xb) {
    int idx = blockIdx.x * 256 + threadIdx.x;
    f32x4 v = *reinterpret_cast<const f32x4*>(x + (size_t)idx * 4);
    s16x4 o;
    o[0] = f2bf(v[0]); o[1] = f2bf(v[1]); o[2] = f2bf(v[2]); o[3] = f2bf(v[3]);
    *reinterpret_cast<s16x4*>(xb + (size_t)idx * 4) = o;
}

// ---------------- wtrans ----------------
__global__ void wtrans_kernel(const float* __restrict__ W, short* __restrict__ Wt) {
    __shared__ float tile[64][65];
    int kb = blockIdx.x, nb = blockIdx.y;
    int t = threadIdx.x;
    int c4 = (t & 15) * 4;
    int r0 = t >> 4;
#pragma unroll
    for (int rr = 0; rr < 4; ++rr) {
        int kl = r0 + rr * 16;
        f32x4 v = *reinterpret_cast<const f32x4*>(W + (size_t)(kb * 64 + kl) * 3072 + nb * 64 + c4);
        tile[kl][c4 + 0] = v[0]; tile[kl][c4 + 1] = v[1];
        tile[kl][c4 + 2] = v[2]; tile[kl][c4 + 3] = v[3];
    }
    __syncthreads();
#pragma unroll
    for (int rr = 0; rr < 4; ++rr) {
        int nl = r0 + rr * 16;
        s16x4 o;
#pragma unroll
        for (int i = 0; i < 4; ++i) o[i] = f2bf(tile[c4 + i][nl]);
        *reinterpret_cast<s16x4*>(Wt + (size_t)(nb * 64 + nl) * 1024 + kb * 64 + c4) = o;
    }
}

// ---------------- qkv_gemm (m97 structure) ----------------
__global__ __launch_bounds__(256) void qkv_gemm_kernel(
    const short* __restrict__ xb, const short* __restrict__ Wt,
    const float* __restrict__ bias,
    short* __restrict__ Qo, short* __restrict__ Ko, short* __restrict__ Vo)
{
    __shared__ short As[128 * 64];
    __shared__ short Bs[128 * 64];
    int tid = threadIdx.x;
    int wave = tid >> 6, lane = tid & 63, g = lane >> 4, lr = lane & 15;
    int wr = wave >> 1, wc = wave & 1;
    int bm = blockIdx.x, bn = blockIdx.y;

    f32x4 acc[4][4];
#pragma unroll
    for (int a = 0; a < 4; ++a)
#pragma unroll
        for (int b = 0; b < 4; ++b) acc[a][b] = (f32x4){0.f, 0.f, 0.f, 0.f};

    // per-lane staging chunk geometry (pre-swizzled SOURCE, linear LDS dest)
    for (int k0 = 0; k0 < 1024; k0 += 64) {
#pragma unroll
        for (int j = 0; j < 4; ++j) {
            int c = j * 256 + tid;           // chunk 0..1023 (8 bf16 each)
            int row = c >> 3, cc = c & 7;
            int scc = (cc ^ (row & 7)) * 8;  // swizzled source chunk
            gll16(xb + (size_t)(bm * 128 + row) * 1024 + k0 + scc,
                  &As[(j * 256 + wave * 64) * 8]);
            gll16(Wt + (size_t)(bn * 128 + row) * 1024 + k0 + scc,
                  &Bs[(j * 256 + wave * 64) * 8]);
        }
        __syncthreads();

        bf16x8 af[2][4], bfr[2][4];
#pragma unroll
        for (int mt = 0; mt < 4; ++mt) {
            int row = wr * 64 + mt * 16 + lr;
            af[0][mt] = *reinterpret_cast<const bf16x8*>(&As[row * 64 + (((g    ) ^ (lr & 7)) * 8)]);
            af[1][mt] = *reinterpret_cast<const bf16x8*>(&As[row * 64 + (((g + 4) ^ (lr & 7)) * 8)]);
        }
#pragma unroll
        for (int nt = 0; nt < 4; ++nt) {
            int row = wc * 64 + nt * 16 + lr;
            bfr[0][nt] = *reinterpret_cast<const bf16x8*>(&Bs[row * 64 + (((g    ) ^ (lr & 7)) * 8)]);
            bfr[1][nt] = *reinterpret_cast<const bf16x8*>(&Bs[row * 64 + (((g + 4) ^ (lr & 7)) * 8)]);
        }
#pragma unroll
        for (int mt = 0; mt < 4; ++mt)
#pragma unroll
            for (int nt = 0; nt < 4; ++nt) {
                acc[mt][nt] = __builtin_amdgcn_mfma_f32_16x16x32_bf16(af[0][mt], bfr[0][nt], acc[mt][nt], 0, 0, 0);
                acc[mt][nt] = __builtin_amdgcn_mfma_f32_16x16x32_bf16(af[1][mt], bfr[1][nt], acc[mt][nt], 0, 0, 0);
            }
        __syncthreads();
    }

#pragma unroll
    for (int nt = 0; nt < 4; ++nt) {
        int n = bn * 128 + wc * 64 + nt * 16 + lr;
        float bv = bias[n];
        int which = n >> 10;
        int h = (n >> 6) & 15;
        int dd = n & 63;
        short* base = (which == 0) ? Qo : (which == 1) ? Ko : Vo;
#pragma unroll
        for (int mt = 0; mt < 4; ++mt) {
#pragma unroll
            for (int r = 0; r < 4; ++r) {
                int m = bm * 128 + wr * 64 + mt * 16 + g * 4 + r;
                int bb = m >> 11, s = m & 2047;
                float v = acc[mt][nt][r] + bv;
                base[(((size_t)bb * 16 + h) * 2048 + s) * 64 + dd] = f2bf(v);
            }
        }
    }
}

// ---------------- vtrans: V [bh][s][64] -> Vt [bh][64][s] ----------------
__global__ __launch_bounds__(256) void vtrans_kernel(const short* __restrict__ V, short* __restrict__ Vt) {
    __shared__ short t[64][72];
    int st = blockIdx.x, bh = blockIdx.y;
    int tid = threadIdx.x;
#pragma unroll
    for (int j = 0; j < 2; ++j) {
        int c = j * 256 + tid;
        int row = c >> 3, cc = c & 7;
        bf16x8 v = *reinterpret_cast<const bf16x8*>(V + (size_t)((bh * 2048) + st * 64 + row) * 64 + cc * 8);
        *reinterpret_cast<bf16x8*>(&t[row][cc * 8]) = v;
    }
    __syncthreads();
#pragma unroll
    for (int j = 0; j < 2; ++j) {
        int c = j * 256 + tid;
        int d = c >> 3, cs = c & 7;
        bf16x8 o;
#pragma unroll
        for (int i = 0; i < 8; ++i) o[i] = t[cs * 8 + i][d];
        *reinterpret_cast<bf16x8*>(Vt + (size_t)(bh * 64 + d) * 2048 + st * 64 + cs * 8) = o;
    }
}

// ---------------- attn ----------------
// grid (32 qtiles, 32 bh), 4 waves x 16 q-rows, KV tile 64, dbuf LDS.
__global__ __launch_bounds__(256) void attn_kernel(
    const short* __restrict__ Qw, const short* __restrict__ Kw, const short* __restrict__ Vtw,
    const float* __restrict__ attnB, float* __restrict__ out)
{
    __shared__ short Ks [2][64 * 64];   // [key][d], source-swizzled chunks
    __shared__ short Vts[2][64 * 64];   // [d][key], source-swizzled chunks
    __shared__ short Ps [4][16 * 64];   // per-wave P

    int qt = blockIdx.x, bh = blockIdx.y;
    int b = bh >> 4, h = bh & 15;
    int tid = threadIdx.x;
    int wave = tid >> 6, lane = tid & 63, g = lane >> 4, lr = lane & 15;

    const short* Qb = Qw  + (size_t)bh * 2048 * 64;
    const short* Kb = Kw  + (size_t)bh * 2048 * 64;
    const short* Vb = Vtw + (size_t)bh * 64 * 2048;
    const float* Bp = attnB + (size_t)bh * 2048 * 2048;

    int qbase = qt * 64 + wave * 16;

    bf16x8 qf0, qf1;
    {
        const short* qp = Qb + (size_t)(qbase + lr) * 64 + g * 8;
        qf0 = *reinterpret_cast<const bf16x8*>(qp);
        qf1 = *reinterpret_cast<const bf16x8*>(qp + 32);
    }
    const float* brow = Bp + (size_t)(qbase + lr) * 2048 + g * 8;

    f32x4 Os[4], Ob[4];
#pragma unroll
    for (int dt = 0; dt < 4; ++dt) { Os[dt] = (f32x4){0.f,0.f,0.f,0.f}; Ob[dt] = (f32x4){0.f,0.f,0.f,0.f}; }
    float lpart[4] = {0.f, 0.f, 0.f, 0.f};

#define STAGE_KV(buf, ktt) do {                                                   \
    _Pragma("unroll")                                                             \
    for (int j = 0; j < 2; ++j) {                                                 \
        int c = j * 256 + tid;                                                    \
        int row = c >> 3, cc = c & 7;                                             \
        int scc = (cc ^ (row & 7)) * 8;                                           \
        gll16(Kb + (size_t)((ktt) * 64 + row) * 64 + scc,                         \
              &Ks[buf][(j * 256 + wave * 64) * 8]);                               \
        gll16(Vb + (size_t)row * 2048 + (ktt) * 64 + scc,                         \
              &Vts[buf][(j * 256 + wave * 64) * 8]);                              \
    }                                                                             \
} while (0)

    STAGE_KV(0, 0);
    __syncthreads();

    for (int kt = 0; kt < 32; ++kt) {
        int cur = kt & 1;
        if (kt < 31) STAGE_KV(cur ^ 1, kt + 1);

        // bias loads for this tile (consumed after softmax -> latency hidden)
        f32x4 bfl0 = *reinterpret_cast<const f32x4*>(brow + kt * 64);
        f32x4 bfl1 = *reinterpret_cast<const f32x4*>(brow + kt * 64 + 4);
        f32x4 bfl2 = *reinterpret_cast<const f32x4*>(brow + kt * 64 + 32);
        f32x4 bfl3 = *reinterpret_cast<const f32x4*>(brow + kt * 64 + 36);

        // ---- QK^T ----
        f32x4 S[4];
        __builtin_amdgcn_s_setprio(1);
#pragma unroll
        for (int nt = 0; nt < 4; ++nt) {
            int row = nt * 16 + lr;
            bf16x8 kf0 = *reinterpret_cast<const bf16x8*>(&Ks[cur][row * 64 + (((g    ) ^ (lr & 7)) * 8)]);
            bf16x8 kf1 = *reinterpret_cast<const bf16x8*>(&Ks[cur][row * 64 + (((g + 4) ^ (lr & 7)) * 8)]);
            f32x4 s = (f32x4){0.f,0.f,0.f,0.f};
            s = __builtin_amdgcn_mfma_f32_16x16x32_bf16(qf0, kf0, s, 0, 0, 0);
            s = __builtin_amdgcn_mfma_f32_16x16x32_bf16(qf1, kf1, s, 0, 0, 0);
            S[nt] = s;
        }
        __builtin_amdgcn_s_setprio(0);

        // ---- softmax-lite (no max subtraction: exact in f32, |S/8| << 88) ----
#pragma unroll
        for (int nt = 0; nt < 4; ++nt)
#pragma unroll
            for (int r = 0; r < 4; ++r) {
                float p = __expf(S[nt][r] * 0.125f);
                S[nt][r] = p;
                lpart[r] += p;
            }

        // ---- P -> LDS (rearrange C-layout -> A-frag layout) ----
#pragma unroll
        for (int nt = 0; nt < 4; ++nt)
#pragma unroll
            for (int r = 0; r < 4; ++r) {
                int q = g * 4 + r;
                int col = nt * 16 + lr;
                Ps[wave][q * 64 + (((col >> 3) ^ (q & 7)) * 8) + (col & 7)] = f2bf(S[nt][r]);
            }

        // ---- bias -> bf16 A-frags ----
        bf16x8 bbf0, bbf1;
#pragma unroll
        for (int i = 0; i < 4; ++i) {
            bbf0[i]     = f2bf(bfl0[i]);
            bbf0[i + 4] = f2bf(bfl1[i]);
            bbf1[i]     = f2bf(bfl2[i]);
            bbf1[i + 4] = f2bf(bfl3[i]);
        }

        bf16x8 pf0 = *reinterpret_cast<const bf16x8*>(&Ps[wave][lr * 64 + (((g    ) ^ (lr & 7)) * 8)]);
        bf16x8 pf1 = *reinterpret_cast<const bf16x8*>(&Ps[wave][lr * 64 + (((g + 4) ^ (lr & 7)) * 8)]);

        // ---- PV + BV ----
        __builtin_amdgcn_s_setprio(1);
#pragma unroll
        for (int dt = 0; dt < 4; ++dt) {
            int row = dt * 16 + lr;
            bf16x8 v0 = *reinterpret_cast<const bf16x8*>(&Vts[cur][row * 64 + (((g    ) ^ (lr & 7)) * 8)]);
            bf16x8 v1 = *reinterpret_cast<const bf16x8*>(&Vts[cur][row * 64 + (((g + 4) ^ (lr & 7)) * 8)]);
            Os[dt] = __builtin_amdgcn_mfma_f32_16x16x32_bf16(pf0,  v0, Os[dt], 0, 0, 0);
            Os[dt] = __builtin_amdgcn_mfma_f32_16x16x32_bf16(pf1,  v1, Os[dt], 0, 0, 0);
            Ob[dt] = __builtin_amdgcn_mfma_f32_16x16x32_bf16(bbf0, v0, Ob[dt], 0, 0, 0);
            Ob[dt] = __builtin_amdgcn_mfma_f32_16x16x32_bf16(bbf1, v1, Ob[dt], 0, 0, 0);
        }
        __builtin_amdgcn_s_setprio(0);

        __syncthreads();   // drains staging vmcnt; buffers swap
    }
#undef STAGE_KV

    // ---- epilogue ----
#pragma unroll
    for (int r = 0; r < 4; ++r) {
        float l = lpart[r];
        l += __shfl_xor(l, 1);
        l += __shfl_xor(l, 2);
        l += __shfl_xor(l, 4);
        l += __shfl_xor(l, 8);
        float inv = 1.0f / l;
        int q = qbase + g * 4 + r;
#pragma unroll
        for (int dt = 0; dt < 4; ++dt) {
            int dcol = dt * 16 + lr;
            out[((size_t)(b * 2048 + q) * 16 + h) * 64 + dcol] = Os[dt][r] * inv + Ob[dt][r];
        }
    }
}

extern "C" void kernel_launch(void* const* d_in, const int* in_sizes, int n_in,
                              void* d_out, int out_size, void* d_ws, size_t ws_size,
                              hipStream_t stream) {
    const float* x     = (const float*)d_in[0];
    const float* attnB = (const float*)d_in[1];
    const float* W     = (const float*)d_in[2];
    const float* bias  = (const float*)d_in[3];
    float* out = (float*)d_out;

    short* ws = (short*)d_ws;
    short* xb = ws;                // 4,194,304
    short* Wt = xb + 4194304;      // 3,145,728
    short* Q  = Wt + 3145728;      // 4,194,304
    short* K  = Q  + 4194304;      // 4,194,304
    short* V  = K  + 4194304;      // 4,194,304
    short* Vt = V  + 4194304;      // 4,194,304   (~48 MB total)

    conv_x_kernel<<<4096, 256, 0, stream>>>(x, xb);
    wtrans_kernel<<<dim3(16, 48), 256, 0, stream>>>(W, Wt);
    qkv_gemm_kernel<<<dim3(32, 24), 256, 0, stream>>>(xb, Wt, bias, Q, K, V);
    vtrans_kernel<<<dim3(32, 32), 256, 0, stream>>>(V, Vt);
    attn_kernel<<<dim3(32, 32), 256, 0, stream>>>(Q, K, Vt, attnB, out);
}

// Round 3
// 206.569 us; speedup vs baseline: 1.1878x; 1.1065x over previous
//
#include <hip/hip_runtime.h>
#include <hip/hip_bf16.h>

// y = (softmax((xWq)(xWk)^T/8) + B) @ (xWv); b=2 s=2048 d=1024 h=16 hd=64
// conv_x -> wtrans -> qkv_gemm (m97-style) -> vtrans -> attn
// attn: swapped QK^T (lane-local P rows), cvt_pk P/bias packing, bias prefetch
//       1 tile ahead, counted vmcnt(4)+raw s_barrier (bias stays in flight).

typedef __attribute__((ext_vector_type(4))) float  f32x4;
typedef __attribute__((ext_vector_type(8))) short  bf16x8;
typedef __attribute__((ext_vector_type(4))) short  s16x4;

__device__ __forceinline__ short f2bf(float f) {
    __hip_bfloat16 h = __float2bfloat16(f);
    return __builtin_bit_cast(short, h);
}

__device__ __forceinline__ unsigned cvt_pk_bf16(float lo, float hi) {
    unsigned w;
    asm("v_cvt_pk_bf16_f32 %0, %1, %2" : "=v"(w) : "v"(lo), "v"(hi));
    return w;
}

__device__ __forceinline__ void gll16(const short* g, short* l) {
    __builtin_amdgcn_global_load_lds(
        (const __attribute__((address_space(1))) void*)g,
        (__attribute__((address_space(3))) void*)l, 16, 0, 0);
}

// ---------------- conv_x ----------------
__global__ void conv_x_kernel(const float* __restrict__ x, short* __restrict__ xb) {
    int idx = blockIdx.x * 256 + threadIdx.x;
    f32x4 v = *reinterpret_cast<const f32x4*>(x + (size_t)idx * 4);
    s16x4 o;
    o[0] = f2bf(v[0]); o[1] = f2bf(v[1]); o[2] = f2bf(v[2]); o[3] = f2bf(v[3]);
    *reinterpret_cast<s16x4*>(xb + (size_t)idx * 4) = o;
}

// ---------------- wtrans ----------------
__global__ void wtrans_kernel(const float* __restrict__ W, short* __restrict__ Wt) {
    __shared__ float tile[64][65];
    int kb = blockIdx.x, nb = blockIdx.y;
    int t = threadIdx.x;
    int c4 = (t & 15) * 4;
    int r0 = t >> 4;
#pragma unroll
    for (int rr = 0; rr < 4; ++rr) {
        int kl = r0 + rr * 16;
        f32x4 v = *reinterpret_cast<const f32x4*>(W + (size_t)(kb * 64 + kl) * 3072 + nb * 64 + c4);
        tile[kl][c4 + 0] = v[0]; tile[kl][c4 + 1] = v[1];
        tile[kl][c4 + 2] = v[2]; tile[kl][c4 + 3] = v[3];
    }
    __syncthreads();
#pragma unroll
    for (int rr = 0; rr < 4; ++rr) {
        int nl = r0 + rr * 16;
        s16x4 o;
#pragma unroll
        for (int i = 0; i < 4; ++i) o[i] = f2bf(tile[c4 + i][nl]);
        *reinterpret_cast<s16x4*>(Wt + (size_t)(nb * 64 + nl) * 1024 + kb * 64 + c4) = o;
    }
}

// ---------------- qkv_gemm (m97 structure) ----------------
__global__ __launch_bounds__(256) void qkv_gemm_kernel(
    const short* __restrict__ xb, const short* __restrict__ Wt,
    const float* __restrict__ bias,
    short* __restrict__ Qo, short* __restrict__ Ko, short* __restrict__ Vo)
{
    __shared__ short As[128 * 64];
    __shared__ short Bs[128 * 64];
    int tid = threadIdx.x;
    int wave = tid >> 6, lane = tid & 63, g = lane >> 4, lr = lane & 15;
    int wr = wave >> 1, wc = wave & 1;
    int bm = blockIdx.x, bn = blockIdx.y;

    f32x4 acc[4][4];
#pragma unroll
    for (int a = 0; a < 4; ++a)
#pragma unroll
        for (int b = 0; b < 4; ++b) acc[a][b] = (f32x4){0.f, 0.f, 0.f, 0.f};

    for (int k0 = 0; k0 < 1024; k0 += 64) {
#pragma unroll
        for (int j = 0; j < 4; ++j) {
            int c = j * 256 + tid;
            int row = c >> 3, cc = c & 7;
            int scc = (cc ^ (row & 7)) * 8;
            gll16(xb + (size_t)(bm * 128 + row) * 1024 + k0 + scc,
                  &As[(j * 256 + wave * 64) * 8]);
            gll16(Wt + (size_t)(bn * 128 + row) * 1024 + k0 + scc,
                  &Bs[(j * 256 + wave * 64) * 8]);
        }
        __syncthreads();

        bf16x8 af[2][4], bfr[2][4];
#pragma unroll
        for (int mt = 0; mt < 4; ++mt) {
            int row = wr * 64 + mt * 16 + lr;
            af[0][mt] = *reinterpret_cast<const bf16x8*>(&As[row * 64 + (((g    ) ^ (lr & 7)) * 8)]);
            af[1][mt] = *reinterpret_cast<const bf16x8*>(&As[row * 64 + (((g + 4) ^ (lr & 7)) * 8)]);
        }
#pragma unroll
        for (int nt = 0; nt < 4; ++nt) {
            int row = wc * 64 + nt * 16 + lr;
            bfr[0][nt] = *reinterpret_cast<const bf16x8*>(&Bs[row * 64 + (((g    ) ^ (lr & 7)) * 8)]);
            bfr[1][nt] = *reinterpret_cast<const bf16x8*>(&Bs[row * 64 + (((g + 4) ^ (lr & 7)) * 8)]);
        }
#pragma unroll
        for (int mt = 0; mt < 4; ++mt)
#pragma unroll
            for (int nt = 0; nt < 4; ++nt) {
                acc[mt][nt] = __builtin_amdgcn_mfma_f32_16x16x32_bf16(af[0][mt], bfr[0][nt], acc[mt][nt], 0, 0, 0);
                acc[mt][nt] = __builtin_amdgcn_mfma_f32_16x16x32_bf16(af[1][mt], bfr[1][nt], acc[mt][nt], 0, 0, 0);
            }
        __syncthreads();
    }

#pragma unroll
    for (int nt = 0; nt < 4; ++nt) {
        int n = bn * 128 + wc * 64 + nt * 16 + lr;
        float bv = bias[n];
        int which = n >> 10;
        int h = (n >> 6) & 15;
        int dd = n & 63;
        short* base = (which == 0) ? Qo : (which == 1) ? Ko : Vo;
#pragma unroll
        for (int mt = 0; mt < 4; ++mt) {
#pragma unroll
            for (int r = 0; r < 4; ++r) {
                int m = bm * 128 + wr * 64 + mt * 16 + g * 4 + r;
                int bb = m >> 11, s = m & 2047;
                float v = acc[mt][nt][r] + bv;
                base[(((size_t)bb * 16 + h) * 2048 + s) * 64 + dd] = f2bf(v);
            }
        }
    }
}

// ---------------- vtrans: V [bh][s][64] -> Vt [bh][64][s] ----------------
__global__ __launch_bounds__(256) void vtrans_kernel(const short* __restrict__ V, short* __restrict__ Vt) {
    __shared__ short t[64][72];
    int st = blockIdx.x, bh = blockIdx.y;
    int tid = threadIdx.x;
#pragma unroll
    for (int j = 0; j < 2; ++j) {
        int c = j * 256 + tid;
        int row = c >> 3, cc = c & 7;
        bf16x8 v = *reinterpret_cast<const bf16x8*>(V + (size_t)((bh * 2048) + st * 64 + row) * 64 + cc * 8);
        *reinterpret_cast<bf16x8*>(&t[row][cc * 8]) = v;
    }
    __syncthreads();
#pragma unroll
    for (int j = 0; j < 2; ++j) {
        int c = j * 256 + tid;
        int d = c >> 3, cs = c & 7;
        bf16x8 o;
#pragma unroll
        for (int i = 0; i < 8; ++i) o[i] = t[cs * 8 + i][d];
        *reinterpret_cast<bf16x8*>(Vt + (size_t)(bh * 64 + d) * 2048 + st * 64 + cs * 8) = o;
    }
}

// ---------------- attn ----------------
// grid (32 qtiles, 32 bh), 4 waves x 16 q-rows, KV tile 64, dbuf LDS,
// swapped QK^T, bias prefetched 1 tile ahead, counted vmcnt barrier.
__global__ __launch_bounds__(256, 4) void attn_kernel(
    const short* __restrict__ Qw, const short* __restrict__ Kw, const short* __restrict__ Vtw,
    const float* __restrict__ attnB, float* __restrict__ out)
{
    __shared__ short Ks [2][64 * 64];   // [key][d], source-swizzled chunks
    __shared__ short Vts[2][64 * 64];   // [d][key], source-swizzled chunks
    __shared__ short Ps [4][16 * 64];   // per-wave P rows (A-frag layout, swizzled)

    int qt = blockIdx.x, bh = blockIdx.y;
    int b = bh >> 4, h = bh & 15;
    int tid = threadIdx.x;
    int wave = tid >> 6, lane = tid & 63, g = lane >> 4, lr = lane & 15;

    const short* Qb = Qw  + (size_t)bh * 2048 * 64;
    const short* Kb = Kw  + (size_t)bh * 2048 * 64;
    const short* Vb = Vtw + (size_t)bh * 64 * 2048;
    const float* Bp = attnB + (size_t)bh * 2048 * 2048;

    int qbase = qt * 64 + wave * 16;

    bf16x8 qf0, qf1;
    {
        const short* qp = Qb + (size_t)(qbase + lr) * 64 + g * 8;
        qf0 = *reinterpret_cast<const bf16x8*>(qp);
        qf1 = *reinterpret_cast<const bf16x8*>(qp + 32);
    }
    const float* brow = Bp + (size_t)(qbase + lr) * 2048 + g * 8;

    f32x4 Os[4], Ob[4];
#pragma unroll
    for (int dt = 0; dt < 4; ++dt) { Os[dt] = (f32x4){0.f,0.f,0.f,0.f}; Ob[dt] = (f32x4){0.f,0.f,0.f,0.f}; }
    float lsum = 0.f;   // per-lane partial row-sum for q = lr

#define STAGE_KV(buf, ktt) do {                                                   \
    _Pragma("unroll")                                                             \
    for (int j = 0; j < 2; ++j) {                                                 \
        int c = j * 256 + tid;                                                    \
        int row = c >> 3, cc = c & 7;                                             \
        int scc = (cc ^ (row & 7)) * 8;                                           \
        gll16(Kb + (size_t)((ktt) * 64 + row) * 64 + scc,                         \
              &Ks[buf][(j * 256 + wave * 64) * 8]);                               \
        gll16(Vb + (size_t)row * 2048 + (ktt) * 64 + scc,                         \
              &Vts[buf][(j * 256 + wave * 64) * 8]);                              \
    }                                                                             \
} while (0)

    // prologue: stage tile 0, prefetch bias tile 0
    f32x4 bfn0, bfn1, bfn2, bfn3;
    STAGE_KV(0, 0);
    __builtin_amdgcn_sched_barrier(0);
    bfn0 = *reinterpret_cast<const f32x4*>(brow);
    bfn1 = *reinterpret_cast<const f32x4*>(brow + 4);
    bfn2 = *reinterpret_cast<const f32x4*>(brow + 32);
    bfn3 = *reinterpret_cast<const f32x4*>(brow + 36);
    asm volatile("s_waitcnt vmcnt(4)" ::: "memory");
    __builtin_amdgcn_s_barrier();
    __builtin_amdgcn_sched_barrier(0);

    for (int kt = 0; kt < 32; ++kt) {
        int cur = kt & 1;

        // ---- convert bias(kt) (prefetched last iter) to bf16 A-frags ----
        unsigned bb0 = cvt_pk_bf16(bfn0[0], bfn0[1]);
        unsigned bb1 = cvt_pk_bf16(bfn0[2], bfn0[3]);
        unsigned bb2 = cvt_pk_bf16(bfn1[0], bfn1[1]);
        unsigned bb3 = cvt_pk_bf16(bfn1[2], bfn1[3]);
        unsigned bb4 = cvt_pk_bf16(bfn2[0], bfn2[1]);
        unsigned bb5 = cvt_pk_bf16(bfn2[2], bfn2[3]);
        unsigned bb6 = cvt_pk_bf16(bfn3[0], bfn3[1]);
        unsigned bb7 = cvt_pk_bf16(bfn3[2], bfn3[3]);

        // ---- stage K/V(kt+1), then prefetch bias(kt+1) (kept in flight) ----
        if (kt < 31) {
            STAGE_KV(cur ^ 1, kt + 1);
            __builtin_amdgcn_sched_barrier(0);
            const float* bp = brow + (kt + 1) * 64;
            bfn0 = *reinterpret_cast<const f32x4*>(bp);
            bfn1 = *reinterpret_cast<const f32x4*>(bp + 4);
            bfn2 = *reinterpret_cast<const f32x4*>(bp + 32);
            bfn3 = *reinterpret_cast<const f32x4*>(bp + 36);
        }

        // ---- swapped QK^T: C[key][q], lane holds q=lr, keys nt*16+4g+r ----
        f32x4 S[4];
        __builtin_amdgcn_s_setprio(1);
#pragma unroll
        for (int nt = 0; nt < 4; ++nt) {
            int row = nt * 16 + lr;
            bf16x8 kf0 = *reinterpret_cast<const bf16x8*>(&Ks[cur][row * 64 + (((g    ) ^ (lr & 7)) * 8)]);
            bf16x8 kf1 = *reinterpret_cast<const bf16x8*>(&Ks[cur][row * 64 + (((g + 4) ^ (lr & 7)) * 8)]);
            f32x4 s = (f32x4){0.f,0.f,0.f,0.f};
            s = __builtin_amdgcn_mfma_f32_16x16x32_bf16(kf0, qf0, s, 0, 0, 0);
            s = __builtin_amdgcn_mfma_f32_16x16x32_bf16(kf1, qf1, s, 0, 0, 0);
            S[nt] = s;
        }
        __builtin_amdgcn_s_setprio(0);

        // ---- softmax-lite: p = 2^(S * 0.125*log2e), scalar row-sum ----
#pragma unroll
        for (int nt = 0; nt < 4; ++nt)
#pragma unroll
            for (int r = 0; r < 4; ++r) {
                float p = exp2f(S[nt][r] * 0.1803368801111f);
                S[nt][r] = p;
                lsum += p;
            }

        // ---- pack P pairs, write 8x ds_write_b32 to per-wave Ps ----
        short* psw = &Ps[wave][lr * 64];
#pragma unroll
        for (int nt = 0; nt < 4; ++nt)
#pragma unroll
            for (int rp = 0; rp < 2; ++rp) {
                unsigned w = cvt_pk_bf16(S[nt][2 * rp], S[nt][2 * rp + 1]);
                int kp = 8 * nt + 2 * g + rp;
                int bi = kp >> 2, off = kp & 3;
                *reinterpret_cast<unsigned*>(psw + ((bi ^ (lr & 7)) << 3) + off * 2) = w;
            }

        bf16x8 pf0 = *reinterpret_cast<const bf16x8*>(&Ps[wave][lr * 64 + (((g    ) ^ (lr & 7)) * 8)]);
        bf16x8 pf1 = *reinterpret_cast<const bf16x8*>(&Ps[wave][lr * 64 + (((g + 4) ^ (lr & 7)) * 8)]);
        bf16x8 bbf0, bbf1;
        {
            typedef __attribute__((ext_vector_type(4))) unsigned u32x4;
            u32x4 t0 = (u32x4){bb0, bb1, bb2, bb3};
            u32x4 t1 = (u32x4){bb4, bb5, bb6, bb7};
            bbf0 = __builtin_bit_cast(bf16x8, t0);
            bbf1 = __builtin_bit_cast(bf16x8, t1);
        }

        // ---- PV + BV ----
        __builtin_amdgcn_s_setprio(1);
#pragma unroll
        for (int dt = 0; dt < 4; ++dt) {
            int row = dt * 16 + lr;
            bf16x8 v0 = *reinterpret_cast<const bf16x8*>(&Vts[cur][row * 64 + (((g    ) ^ (lr & 7)) * 8)]);
            bf16x8 v1 = *reinterpret_cast<const bf16x8*>(&Vts[cur][row * 64 + (((g + 4) ^ (lr & 7)) * 8)]);
            Os[dt] = __builtin_amdgcn_mfma_f32_16x16x32_bf16(pf0,  v0, Os[dt], 0, 0, 0);
            Os[dt] = __builtin_amdgcn_mfma_f32_16x16x32_bf16(pf1,  v1, Os[dt], 0, 0, 0);
            Ob[dt] = __builtin_amdgcn_mfma_f32_16x16x32_bf16(bbf0, v0, Ob[dt], 0, 0, 0);
            Ob[dt] = __builtin_amdgcn_mfma_f32_16x16x32_bf16(bbf1, v1, Ob[dt], 0, 0, 0);
        }
        __builtin_amdgcn_s_setprio(0);

        if (kt < 31) {
            // stage K/V(kt+1) done; 4 bias loads stay in flight across barrier
            asm volatile("s_waitcnt vmcnt(4)" ::: "memory");
            __builtin_amdgcn_s_barrier();
            __builtin_amdgcn_sched_barrier(0);
        }
    }
#undef STAGE_KV

    // ---- epilogue: reduce row sums across the 4 lane-groups ----
    float l = lsum;
    l += __shfl_xor(l, 16);
    l += __shfl_xor(l, 32);
    float inv = 1.0f / l;          // lane holds inv for q = lr
#pragma unroll
    for (int r = 0; r < 4; ++r) {
        float invr = __shfl(inv, g * 4 + r);   // inv for q = 4g + r
        int q = qbase + g * 4 + r;
#pragma unroll
        for (int dt = 0; dt < 4; ++dt) {
            int dcol = dt * 16 + lr;
            out[((size_t)(b * 2048 + q) * 16 + h) * 64 + dcol] = Os[dt][r] * invr + Ob[dt][r];
        }
    }
}

extern "C" void kernel_launch(void* const* d_in, const int* in_sizes, int n_in,
                              void* d_out, int out_size, void* d_ws, size_t ws_size,
                              hipStream_t stream) {
    const float* x     = (const float*)d_in[0];
    const float* attnB = (const float*)d_in[1];
    const float* W     = (const float*)d_in[2];
    const float* bias  = (const float*)d_in[3];
    float* out = (float*)d_out;

    short* ws = (short*)d_ws;
    short* xb = ws;                // 4,194,304
    short* Wt = xb + 4194304;      // 3,145,728
    short* Q  = Wt + 3145728;      // 4,194,304
    short* K  = Q  + 4194304;      // 4,194,304
    short* V  = K  + 4194304;      // 4,194,304
    short* Vt = V  + 4194304;      // 4,194,304

    conv_x_kernel<<<4096, 256, 0, stream>>>(x, xb);
    wtrans_kernel<<<dim3(16, 48), 256, 0, stream>>>(W, Wt);
    qkv_gemm_kernel<<<dim3(32, 24), 256, 0, stream>>>(xb, Wt, bias, Q, K, V);
    vtrans_kernel<<<dim3(32, 32), 256, 0, stream>>>(V, Vt);
    attn_kernel<<<dim3(32, 32), 256, 0, stream>>>(Q, K, Vt, attnB, out);
}

// Round 4
// 205.453 us; speedup vs baseline: 1.1943x; 1.0054x over previous
//
#include <hip/hip_runtime.h>
#include <hip/hip_bf16.h>

// y = (softmax((xWq)(xWk)^T/8) + B) @ (xWv); b=2 s=2048 d=1024 h=16 hd=64
// conv_x -> wtrans -> qkv_gemm (m97-style) -> vtrans -> attn
// attn: qtile=128 (8 waves x 16 q-rows), bh-clustered XCD swizzle (K/V L2-
//       resident per XCD), dbuf LDS, swapped QK^T, cvt_pk packing, bias
//       prefetch 1 tile ahead w/ counted vmcnt(4), nontemporal bias/out.

typedef __attribute__((ext_vector_type(4))) float  f32x4;
typedef __attribute__((ext_vector_type(8))) short  bf16x8;
typedef __attribute__((ext_vector_type(4))) short  s16x4;
typedef __attribute__((ext_vector_type(4))) unsigned u32x4;

__device__ __forceinline__ short f2bf(float f) {
    __hip_bfloat16 h = __float2bfloat16(f);
    return __builtin_bit_cast(short, h);
}

__device__ __forceinline__ unsigned cvt_pk_bf16(float lo, float hi) {
    unsigned w;
    asm("v_cvt_pk_bf16_f32 %0, %1, %2" : "=v"(w) : "v"(lo), "v"(hi));
    return w;
}

__device__ __forceinline__ void gll16(const short* g, short* l) {
    __builtin_amdgcn_global_load_lds(
        (const __attribute__((address_space(1))) void*)g,
        (__attribute__((address_space(3))) void*)l, 16, 0, 0);
}

// ---------------- conv_x ----------------
__global__ void conv_x_kernel(const float* __restrict__ x, short* __restrict__ xb) {
    int idx = blockIdx.x * 256 + threadIdx.x;
    f32x4 v = *reinterpret_cast<const f32x4*>(x + (size_t)idx * 4);
    s16x4 o;
    o[0] = f2bf(v[0]); o[1] = f2bf(v[1]); o[2] = f2bf(v[2]); o[3] = f2bf(v[3]);
    *reinterpret_cast<s16x4*>(xb + (size_t)idx * 4) = o;
}

// ---------------- wtrans ----------------
__global__ void wtrans_kernel(const float* __restrict__ W, short* __restrict__ Wt) {
    __shared__ float tile[64][65];
    int kb = blockIdx.x, nb = blockIdx.y;
    int t = threadIdx.x;
    int c4 = (t & 15) * 4;
    int r0 = t >> 4;
#pragma unroll
    for (int rr = 0; rr < 4; ++rr) {
        int kl = r0 + rr * 16;
        f32x4 v = *reinterpret_cast<const f32x4*>(W + (size_t)(kb * 64 + kl) * 3072 + nb * 64 + c4);
        tile[kl][c4 + 0] = v[0]; tile[kl][c4 + 1] = v[1];
        tile[kl][c4 + 2] = v[2]; tile[kl][c4 + 3] = v[3];
    }
    __syncthreads();
#pragma unroll
    for (int rr = 0; rr < 4; ++rr) {
        int nl = r0 + rr * 16;
        s16x4 o;
#pragma unroll
        for (int i = 0; i < 4; ++i) o[i] = f2bf(tile[c4 + i][nl]);
        *reinterpret_cast<s16x4*>(Wt + (size_t)(nb * 64 + nl) * 1024 + kb * 64 + c4) = o;
    }
}

// ---------------- qkv_gemm (m97 structure) ----------------
__global__ __launch_bounds__(256) void qkv_gemm_kernel(
    const short* __restrict__ xb, const short* __restrict__ Wt,
    const float* __restrict__ bias,
    short* __restrict__ Qo, short* __restrict__ Ko, short* __restrict__ Vo)
{
    __shared__ short As[128 * 64];
    __shared__ short Bs[128 * 64];
    int tid = threadIdx.x;
    int wave = tid >> 6, lane = tid & 63, g = lane >> 4, lr = lane & 15;
    int wr = wave >> 1, wc = wave & 1;
    int bm = blockIdx.x, bn = blockIdx.y;

    f32x4 acc[4][4];
#pragma unroll
    for (int a = 0; a < 4; ++a)
#pragma unroll
        for (int b = 0; b < 4; ++b) acc[a][b] = (f32x4){0.f, 0.f, 0.f, 0.f};

    for (int k0 = 0; k0 < 1024; k0 += 64) {
#pragma unroll
        for (int j = 0; j < 4; ++j) {
            int c = j * 256 + tid;
            int row = c >> 3, cc = c & 7;
            int scc = (cc ^ (row & 7)) * 8;
            gll16(xb + (size_t)(bm * 128 + row) * 1024 + k0 + scc,
                  &As[(j * 256 + wave * 64) * 8]);
            gll16(Wt + (size_t)(bn * 128 + row) * 1024 + k0 + scc,
                  &Bs[(j * 256 + wave * 64) * 8]);
        }
        __syncthreads();

        bf16x8 af[2][4], bfr[2][4];
#pragma unroll
        for (int mt = 0; mt < 4; ++mt) {
            int row = wr * 64 + mt * 16 + lr;
            af[0][mt] = *reinterpret_cast<const bf16x8*>(&As[row * 64 + (((g    ) ^ (lr & 7)) * 8)]);
            af[1][mt] = *reinterpret_cast<const bf16x8*>(&As[row * 64 + (((g + 4) ^ (lr & 7)) * 8)]);
        }
#pragma unroll
        for (int nt = 0; nt < 4; ++nt) {
            int row = wc * 64 + nt * 16 + lr;
            bfr[0][nt] = *reinterpret_cast<const bf16x8*>(&Bs[row * 64 + (((g    ) ^ (lr & 7)) * 8)]);
            bfr[1][nt] = *reinterpret_cast<const bf16x8*>(&Bs[row * 64 + (((g + 4) ^ (lr & 7)) * 8)]);
        }
#pragma unroll
        for (int mt = 0; mt < 4; ++mt)
#pragma unroll
            for (int nt = 0; nt < 4; ++nt) {
                acc[mt][nt] = __builtin_amdgcn_mfma_f32_16x16x32_bf16(af[0][mt], bfr[0][nt], acc[mt][nt], 0, 0, 0);
                acc[mt][nt] = __builtin_amdgcn_mfma_f32_16x16x32_bf16(af[1][mt], bfr[1][nt], acc[mt][nt], 0, 0, 0);
            }
        __syncthreads();
    }

#pragma unroll
    for (int nt = 0; nt < 4; ++nt) {
        int n = bn * 128 + wc * 64 + nt * 16 + lr;
        float bv = bias[n];
        int which = n >> 10;
        int h = (n >> 6) & 15;
        int dd = n & 63;
        short* base = (which == 0) ? Qo : (which == 1) ? Ko : Vo;
#pragma unroll
        for (int mt = 0; mt < 4; ++mt) {
#pragma unroll
            for (int r = 0; r < 4; ++r) {
                int m = bm * 128 + wr * 64 + mt * 16 + g * 4 + r;
                int bb = m >> 11, s = m & 2047;
                float v = acc[mt][nt][r] + bv;
                base[(((size_t)bb * 16 + h) * 2048 + s) * 64 + dd] = f2bf(v);
            }
        }
    }
}

// ---------------- vtrans: V [bh][s][64] -> Vt [bh][64][s] ----------------
__global__ __launch_bounds__(256) void vtrans_kernel(const short* __restrict__ V, short* __restrict__ Vt) {
    __shared__ short t[64][72];
    int st = blockIdx.x, bh = blockIdx.y;
    int tid = threadIdx.x;
#pragma unroll
    for (int j = 0; j < 2; ++j) {
        int c = j * 256 + tid;
        int row = c >> 3, cc = c & 7;
        bf16x8 v = *reinterpret_cast<const bf16x8*>(V + (size_t)((bh * 2048) + st * 64 + row) * 64 + cc * 8);
        *reinterpret_cast<bf16x8*>(&t[row][cc * 8]) = v;
    }
    __syncthreads();
#pragma unroll
    for (int j = 0; j < 2; ++j) {
        int c = j * 256 + tid;
        int d = c >> 3, cs = c & 7;
        bf16x8 o;
#pragma unroll
        for (int i = 0; i < 8; ++i) o[i] = t[cs * 8 + i][d];
        *reinterpret_cast<bf16x8*>(Vt + (size_t)(bh * 64 + d) * 2048 + st * 64 + cs * 8) = o;
    }
}

// ---------------- attn ----------------
// grid 512 linear; id = (bh&7) + 8*(qt + 16*(bh>>3)) so XCD(id%8)==bh%8:
// all 16 q-blocks of a bh co-resident on one XCD -> K/V fetched once per bh.
// 512 threads = 8 waves x 16 q-rows (qtile 128), KV tile 64, dbuf LDS.
__global__ __launch_bounds__(512, 4) void attn_kernel(
    const short* __restrict__ Qw, const short* __restrict__ Kw, const short* __restrict__ Vtw,
    const float* __restrict__ attnB, float* __restrict__ out)
{
    __shared__ short Ks [2][64 * 64];   // [key][d], source-swizzled chunks
    __shared__ short Vts[2][64 * 64];   // [d][key], source-swizzled chunks
    __shared__ short Ps [8][16 * 64];   // per-wave P rows (A-frag layout, swizzled)

    int id = blockIdx.x;
    int bh3 = id & 7;
    int qt  = (id >> 3) & 15;
    int bh  = ((id >> 7) << 3) | bh3;   // bh = (bh>>3)*8 + bh&7
    int b = bh >> 4, h = bh & 15;
    int tid = threadIdx.x;
    int wave = tid >> 6, lane = tid & 63, g = lane >> 4, lr = lane & 15;

    const short* Qb = Qw  + (size_t)bh * 2048 * 64;
    const short* Kb = Kw  + (size_t)bh * 2048 * 64;
    const short* Vb = Vtw + (size_t)bh * 64 * 2048;
    const float* Bp = attnB + (size_t)bh * 2048 * 2048;

    int qbase = qt * 128 + wave * 16;

    bf16x8 qf0, qf1;
    {
        const short* qp = Qb + (size_t)(qbase + lr) * 64 + g * 8;
        qf0 = *reinterpret_cast<const bf16x8*>(qp);
        qf1 = *reinterpret_cast<const bf16x8*>(qp + 32);
    }
    const float* brow = Bp + (size_t)(qbase + lr) * 2048 + g * 8;

    f32x4 Os[4], Ob[4];
#pragma unroll
    for (int dt = 0; dt < 4; ++dt) { Os[dt] = (f32x4){0.f,0.f,0.f,0.f}; Ob[dt] = (f32x4){0.f,0.f,0.f,0.f}; }
    float lsum = 0.f;   // per-lane partial row-sum for q = lr

    // 512 threads stage 512 K-chunks + 512 V-chunks (1 each)
#define STAGE_KV(buf, ktt) do {                                                   \
    int row = tid >> 3, cc = tid & 7;                                             \
    int scc = (cc ^ (row & 7)) * 8;                                               \
    gll16(Kb + (size_t)((ktt) * 64 + row) * 64 + scc,                             \
          &Ks[buf][wave * 512]);                                                  \
    gll16(Vb + (size_t)row * 2048 + (ktt) * 64 + scc,                             \
          &Vts[buf][wave * 512]);                                                 \
} while (0)

    // prologue: stage tile 0, prefetch bias tile 0
    f32x4 bfn0, bfn1, bfn2, bfn3;
    STAGE_KV(0, 0);
    __builtin_amdgcn_sched_barrier(0);
    bfn0 = __builtin_nontemporal_load(reinterpret_cast<const f32x4*>(brow));
    bfn1 = __builtin_nontemporal_load(reinterpret_cast<const f32x4*>(brow + 4));
    bfn2 = __builtin_nontemporal_load(reinterpret_cast<const f32x4*>(brow + 32));
    bfn3 = __builtin_nontemporal_load(reinterpret_cast<const f32x4*>(brow + 36));
    asm volatile("s_waitcnt vmcnt(4)" ::: "memory");
    __builtin_amdgcn_s_barrier();
    __builtin_amdgcn_sched_barrier(0);

    for (int kt = 0; kt < 32; ++kt) {
        int cur = kt & 1;

        // ---- convert bias(kt) (prefetched last iter) to bf16 A-frags ----
        unsigned bb0 = cvt_pk_bf16(bfn0[0], bfn0[1]);
        unsigned bb1 = cvt_pk_bf16(bfn0[2], bfn0[3]);
        unsigned bb2 = cvt_pk_bf16(bfn1[0], bfn1[1]);
        unsigned bb3 = cvt_pk_bf16(bfn1[2], bfn1[3]);
        unsigned bb4 = cvt_pk_bf16(bfn2[0], bfn2[1]);
        unsigned bb5 = cvt_pk_bf16(bfn2[2], bfn2[3]);
        unsigned bb6 = cvt_pk_bf16(bfn3[0], bfn3[1]);
        unsigned bb7 = cvt_pk_bf16(bfn3[2], bfn3[3]);

        // ---- stage K/V(kt+1), then prefetch bias(kt+1) (kept in flight) ----
        if (kt < 31) {
            STAGE_KV(cur ^ 1, kt + 1);
            __builtin_amdgcn_sched_barrier(0);
            const float* bp = brow + (kt + 1) * 64;
            bfn0 = __builtin_nontemporal_load(reinterpret_cast<const f32x4*>(bp));
            bfn1 = __builtin_nontemporal_load(reinterpret_cast<const f32x4*>(bp + 4));
            bfn2 = __builtin_nontemporal_load(reinterpret_cast<const f32x4*>(bp + 32));
            bfn3 = __builtin_nontemporal_load(reinterpret_cast<const f32x4*>(bp + 36));
        }

        // ---- swapped QK^T: C[key][q], lane holds q=lr, keys nt*16+4g+r ----
        f32x4 S[4];
        __builtin_amdgcn_s_setprio(1);
#pragma unroll
        for (int nt = 0; nt < 4; ++nt) {
            int row = nt * 16 + lr;
            bf16x8 kf0 = *reinterpret_cast<const bf16x8*>(&Ks[cur][row * 64 + (((g    ) ^ (lr & 7)) * 8)]);
            bf16x8 kf1 = *reinterpret_cast<const bf16x8*>(&Ks[cur][row * 64 + (((g + 4) ^ (lr & 7)) * 8)]);
            f32x4 s = (f32x4){0.f,0.f,0.f,0.f};
            s = __builtin_amdgcn_mfma_f32_16x16x32_bf16(kf0, qf0, s, 0, 0, 0);
            s = __builtin_amdgcn_mfma_f32_16x16x32_bf16(kf1, qf1, s, 0, 0, 0);
            S[nt] = s;
        }
        __builtin_amdgcn_s_setprio(0);

        // ---- softmax-lite: p = 2^(S * 0.125*log2e), scalar row-sum ----
#pragma unroll
        for (int nt = 0; nt < 4; ++nt)
#pragma unroll
            for (int r = 0; r < 4; ++r) {
                float p = exp2f(S[nt][r] * 0.1803368801111f);
                S[nt][r] = p;
                lsum += p;
            }

        // ---- pack P pairs, write 8x ds_write_b32 to per-wave Ps ----
        short* psw = &Ps[wave][lr * 64];
#pragma unroll
        for (int nt = 0; nt < 4; ++nt)
#pragma unroll
            for (int rp = 0; rp < 2; ++rp) {
                unsigned w = cvt_pk_bf16(S[nt][2 * rp], S[nt][2 * rp + 1]);
                int kp = 8 * nt + 2 * g + rp;
                int bi = kp >> 2, off = kp & 3;
                *reinterpret_cast<unsigned*>(psw + ((bi ^ (lr & 7)) << 3) + off * 2) = w;
            }

        bf16x8 pf0 = *reinterpret_cast<const bf16x8*>(&Ps[wave][lr * 64 + (((g    ) ^ (lr & 7)) * 8)]);
        bf16x8 pf1 = *reinterpret_cast<const bf16x8*>(&Ps[wave][lr * 64 + (((g + 4) ^ (lr & 7)) * 8)]);
        bf16x8 bbf0, bbf1;
        {
            u32x4 t0 = (u32x4){bb0, bb1, bb2, bb3};
            u32x4 t1 = (u32x4){bb4, bb5, bb6, bb7};
            bbf0 = __builtin_bit_cast(bf16x8, t0);
            bbf1 = __builtin_bit_cast(bf16x8, t1);
        }

        // ---- PV + BV ----
        __builtin_amdgcn_s_setprio(1);
#pragma unroll
        for (int dt = 0; dt < 4; ++dt) {
            int row = dt * 16 + lr;
            bf16x8 v0 = *reinterpret_cast<const bf16x8*>(&Vts[cur][row * 64 + (((g    ) ^ (lr & 7)) * 8)]);
            bf16x8 v1 = *reinterpret_cast<const bf16x8*>(&Vts[cur][row * 64 + (((g + 4) ^ (lr & 7)) * 8)]);
            Os[dt] = __builtin_amdgcn_mfma_f32_16x16x32_bf16(pf0,  v0, Os[dt], 0, 0, 0);
            Os[dt] = __builtin_amdgcn_mfma_f32_16x16x32_bf16(pf1,  v1, Os[dt], 0, 0, 0);
            Ob[dt] = __builtin_amdgcn_mfma_f32_16x16x32_bf16(bbf0, v0, Ob[dt], 0, 0, 0);
            Ob[dt] = __builtin_amdgcn_mfma_f32_16x16x32_bf16(bbf1, v1, Ob[dt], 0, 0, 0);
        }
        __builtin_amdgcn_s_setprio(0);

        if (kt < 31) {
            // stage K/V(kt+1) done; 4 bias loads stay in flight across barrier
            asm volatile("s_waitcnt vmcnt(4)" ::: "memory");
            __builtin_amdgcn_s_barrier();
            __builtin_amdgcn_sched_barrier(0);
        }
    }
#undef STAGE_KV

    // ---- epilogue: reduce row sums across the 4 lane-groups ----
    float l = lsum;
    l += __shfl_xor(l, 16);
    l += __shfl_xor(l, 32);
    float inv = 1.0f / l;          // lane holds inv for q = lr
#pragma unroll
    for (int r = 0; r < 4; ++r) {
        float invr = __shfl(inv, g * 4 + r);   // inv for q = 4g + r
        int q = qbase + g * 4 + r;
#pragma unroll
        for (int dt = 0; dt < 4; ++dt) {
            int dcol = dt * 16 + lr;
            float v = Os[dt][r] * invr + Ob[dt][r];
            __builtin_nontemporal_store(v, &out[((size_t)(b * 2048 + q) * 16 + h) * 64 + dcol]);
        }
    }
}

extern "C" void kernel_launch(void* const* d_in, const int* in_sizes, int n_in,
                              void* d_out, int out_size, void* d_ws, size_t ws_size,
                              hipStream_t stream) {
    const float* x     = (const float*)d_in[0];
    const float* attnB = (const float*)d_in[1];
    const float* W     = (const float*)d_in[2];
    const float* bias  = (const float*)d_in[3];
    float* out = (float*)d_out;

    short* ws = (short*)d_ws;
    short* xb = ws;                // 4,194,304
    short* Wt = xb + 4194304;      // 3,145,728
    short* Q  = Wt + 3145728;      // 4,194,304
    short* K  = Q  + 4194304;      // 4,194,304
    short* V  = K  + 4194304;      // 4,194,304
    short* Vt = V  + 4194304;      // 4,194,304

    conv_x_kernel<<<4096, 256, 0, stream>>>(x, xb);
    wtrans_kernel<<<dim3(16, 48), 256, 0, stream>>>(W, Wt);
    qkv_gemm_kernel<<<dim3(32, 24), 256, 0, stream>>>(xb, Wt, bias, Q, K, V);
    vtrans_kernel<<<dim3(32, 32), 256, 0, stream>>>(V, Vt);
    attn_kernel<<<512, 512, 0, stream>>>(Q, K, Vt, attnB, out);
}